// Round 3
// baseline (149.945 us; speedup 1.0000x reference)
//
#include <hip/hip_runtime.h>
#include <math.h>

// DCN v2: B=8, C=128, O=128, H=W=64, k=3, dil=1, dg=1, stride=1, pad=1.
// R11 = R10 with the f16 type fix: __builtin_amdgcn_cvt_pkrtz returns an
// __fp16 vector and the f16 MFMA builtins take __fp16 vectors; _Float16
// vectors do NOT lax-convert to them. So: h2 (_Float16x2) for packed
// arithmetic, f16x8 (__fp16x8, storage-only) for MFMA operands, and pkh()
// goes through decltype+union.
//  - f16 data path: v_pk_fma_f16 bilinear interp (4 ops per channel-pair vs
//    ~17), mfma_f32_16x16x32_f16 GEMM, cvt_pkrtz packing.
//  - pband row stride 68 (not 64): bank = (4*row + x) % 32, so per-lane row
//    jitter decorrelates the data-dependent gather conflicts (64 % 32 == 0
//    made row invisible to the bank index).
//  - AST=84: B-fragments via ds_read_b128 (16B-aligned, stride 84 -> 2-way
//    free), ash writes via 2x ds_write_b128.
//  - whole-granule A prefetch pa[5][2] (40 VGPR), loaded one granule ahead.
// LDS 67,200 B -> still 2 blocks/CU. __launch_bounds__(512,4) caps VGPR 128.
constexpr int Bn = 8, Cn = 128, On = 128, Hn = 64, Wn = 64;
constexpr int KK = 9, PAD = 1;
constexpr int BDIM = 512;                 // 8 waves
constexpr int PXB  = 64;                  // full row per block
constexpr int CG = 16, NG = Cn / CG;      // 8 channel granules
constexpr int KG = 160, KTOT = NG * KG;   // 1280 (144 real + 16 pad per granule)
constexpr int BANDH = 11;                 // band rows (h-5 .. h+5)
constexpr int RST  = 68;                  // pband row stride (dwords)
constexpr int XSTP = 756;                 // pband pair stride (dwords), 16B-aligned
constexpr int AST  = 84;                  // ash px stride (dwords), 16B-aligned
constexpr int ME   = KK * PXB;            // 576 sampling elements
constexpr int PB_DW  = 8 * XSTP;          // 6048
constexpr int ASH_DW = PXB * AST;         // 5376
constexpr int SM_DW  = PB_DW + 2 * ASH_DW;// 16800 dwords = 67,200 B
constexpr int BUNITS = BANDH * 128;       // 1408 band load/write units

typedef __attribute__((ext_vector_type(2))) _Float16 h2;      // arithmetic
typedef __attribute__((ext_vector_type(8))) __fp16   f16x8;   // MFMA operand
typedef __attribute__((ext_vector_type(4))) float f32x4;
typedef unsigned short u16;
typedef unsigned int u32;

union UH  { u32 u; h2 h; };
union U4H { uint4 u; f16x8 h; };

__device__ __forceinline__ u32 pkh(float a, float b) {  // low16 = f16(a), RTZ
    union { decltype(__builtin_amdgcn_cvt_pkrtz(0.f, 0.f)) p; u32 u; } t;
    t.p = __builtin_amdgcn_cvt_pkrtz(a, b);
    return t.u;
}
__device__ __forceinline__ h2 bch(u32 w) { UH t; t.u = w; return t.h; }
__device__ __forceinline__ u16 f2h(float f) {           // RNE f32->f16
    union { _Float16 h; u16 u; } v; v.h = (_Float16)f; return v.u;
}

// weight [O][C*9] fp32 -> wh [O][KTOT] f16, k' = g*KG + t*16 + cl.
// One block per o: coalesced reads, LDS bounce, coalesced u32 stores.
__global__ void wprep_kernel(const float* __restrict__ w, u16* __restrict__ wh) {
    __shared__ u32 tmpw[KTOT / 2];
    u16* tmp = (u16*)tmpw;
    const int tid = threadIdx.x, o = blockIdx.x;
    if (tid < 64)    // zero pad slices k=144..159 of each granule (dwords 72..79)
        tmpw[(tid >> 3) * 80 + 72 + (tid & 7)] = 0;
    for (int k = tid; k < Cn * KK; k += 256) {
        const int c = k / 9, t = k - 9 * c;
        tmp[(c >> 4) * KG + t * 16 + (c & 15)] = f2h(w[o * (Cn * KK) + k]);
    }
    __syncthreads();
    u32* dst = (u32*)(wh + (size_t)o * KTOT);
    for (int e = tid; e < KTOT / 2; e += 256) dst[e] = tmpw[e];
}

// sampling of one (tap,px) element for one 16-channel granule.
// wp: 4x u32, each = bilinear weight duplicated as packed f16 pair.
__device__ __forceinline__ void do_sample(const u32* __restrict__ pband,
                                          u32* __restrict__ ashW,
                                          const float* __restrict__ xg,
                                          const uint4 wp, const int2 q,
                                          const int2 ix, const int e)
{
    const int t = e >> 6, px = e & 63;
    u32 avp[8];
    if (!__any((q.x | q.y) < 0)) {           // all corners of wave in band
        const u32* p0 = pband + ix.x;
        const u32* p1 = pband + ix.y;
        const h2 w0 = bch(wp.x), w1 = bch(wp.y), w2 = bch(wp.z), w3 = bch(wp.w);
        #pragma unroll
        for (int c2 = 0; c2 < 8; ++c2) {
            const h2 vt0 = bch(p0[c2 * XSTP]), vt1 = bch(p0[c2 * XSTP + 1]);
            const h2 vb0 = bch(p1[c2 * XSTP]), vb1 = bch(p1[c2 * XSTP + 1]);
            const h2 r = w0 * vt0 + w1 * vt1 + w2 * vb0 + w3 * vb1;
            UH o; o.h = r; avp[c2] = o.u;
        }
    } else {                                  // rare: clamped global reads
        const float fw0 = (float)bch(wp.x)[0], fw1 = (float)bch(wp.y)[0];
        const float fw2 = (float)bch(wp.z)[0], fw3 = (float)bch(wp.w)[0];
        const int qx = q.x < 0 ? ~q.x : q.x;
        const int qy = q.y < 0 ? ~q.y : q.y;
        const int yrx = qx >> 8, yry = qy >> 8;
        const int xx = (qx & 255) - 1, xy = (qy & 255) - 1;
        const int ax0 = max(xx, 0), ax1 = min(xx + 1, Wn - 1);
        const int ay0 = max(xy, 0), ay1 = min(xy + 1, Wn - 1);
        #pragma unroll
        for (int c2 = 0; c2 < 8; ++c2) {
            float v2[2];
            #pragma unroll
            for (int sb = 0; sb < 2; ++sb) {
                const float* gc = xg + ((2 * c2 + sb) << 12);
                const float t0 = gc[yrx * Wn + ax0], t1 = gc[yrx * Wn + ax1];
                const float b0 = gc[yry * Wn + ay0], b1 = gc[yry * Wn + ay1];
                v2[sb] = fmaf(fw0, t0, fmaf(fw1, t1, fmaf(fw2, b0, fw3 * b1)));
            }
            avp[c2] = pkh(v2[0], v2[1]);
        }
    }
    u32* d = ashW + px * AST + t * 8;
    *(uint4*)&d[0] = make_uint4(avp[0], avp[1], avp[2], avp[3]);
    *(uint4*)&d[4] = make_uint4(avp[4], avp[5], avp[6], avp[7]);
}

__global__ __launch_bounds__(BDIM, 4)
void dcn_mfma_kernel(const float* __restrict__ x,
                     const float* __restrict__ offs,
                     const float* __restrict__ mask,
                     const u16*   __restrict__ wh,
                     const float* __restrict__ bias,
                     float* __restrict__ out)
{
    __shared__ __align__(16) u32 smem[SM_DW];   // pband | ash0 | ash1
    u32* const pband = smem;

    const int tid = threadIdx.x;
    const int b   = blockIdx.x & 7;             // batch <-> XCD affinity
    const int h   = blockIdx.x >> 3;
    const int r0  = min(max(h - 5, 0), Hn - BANDH);

    const int s_px4 = tid & 15, s_pair = (tid >> 4) & 7;

    float4 bnda[3], bndb[3];
#define BLOAD(GCH) { \
        _Pragma("unroll") \
        for (int it = 0; it < 3; ++it) { \
            const int u = tid + it * BDIM; \
            if (u < BUNITS) { \
                const int row = u >> 7; \
                const float* bp = x + (((size_t)(b * Cn + (GCH) * CG + 2 * s_pair)) << 12) \
                                  + (r0 + row) * Wn + (s_px4 << 2); \
                bnda[it] = *(const float4*)bp; \
                bndb[it] = *(const float4*)(bp + 4096); \
            } \
        } }
#define BWRITE() { \
        _Pragma("unroll") \
        for (int it = 0; it < 3; ++it) { \
            const int u = tid + it * BDIM; \
            if (u < BUNITS) { \
                const int row = u >> 7; \
                u32* d = &pband[s_pair * XSTP + row * RST + 8 + (s_px4 << 2)]; \
                *(uint4*)d = make_uint4( \
                    pkh(bnda[it].x, bndb[it].x), pkh(bnda[it].y, bndb[it].y), \
                    pkh(bnda[it].z, bndb[it].z), pkh(bnda[it].w, bndb[it].w)); \
            } \
        } }

    BLOAD(0);   // issue granule-0 band loads before meta (latency overlap)

    // ---- meta in registers: packed f16 weights mwp, coord code mq, index mi ----
    uint4 mwp[2]; int2 mq[2]; int2 mi[2];
    #pragma unroll
    for (int it = 0; it < 2; ++it) {
        mwp[it] = make_uint4(0, 0, 0, 0);
        mq[it] = make_int2(r0 << 8, r0 << 8);
        mi[it] = make_int2(7, 7);
        const int e = tid + it * BDIM;
        if (e < ME) {
            const int t = e >> 6, px = e & 63;
            const int ty = t / 3, tx = t - ty * 3;
            const float oy = offs[((b * 18 + 2 * t    ) * Hn + h) * Wn + px];
            const float ox = offs[((b * 18 + 2 * t + 1) * Hn + h) * Wn + px];
            const float m  = mask[((b * KK + t) * Hn + h) * Wn + px];
            const float py = (float)(h - PAD + ty) + oy;
            const float qx = (float)(px - PAD + tx) + ox;
            const float fy = floorf(py), fx = floorf(qx);
            const float wy1 = py - fy, wx1 = qx - fx;
            const float wy0 = 1.f - wy1, wx0 = 1.f - wx1;
            const int y0 = (int)fy, x0 = (int)fx;
            const bool cx0 = (x0 >= 0) && (x0 < Wn);
            const bool cx1 = (x0 >= -1) && (x0 < Wn - 1);
            const float wr[2] = { wy0, wy1 };
            float wout[4]; int qout[2], iout[2];
            #pragma unroll
            for (int j = 0; j < 2; ++j) {
                const int yr = y0 + j;
                const bool rv = (yr >= 0) && (yr < Hn);
                wout[2 * j]     = (rv && cx0) ? wr[j] * wx0 * m : 0.f;
                wout[2 * j + 1] = (rv && cx1) ? wr[j] * wx1 * m : 0.f;
                int qv;
                if (!rv || (!cx0 && !cx1)) qv = r0 << 8;   // junk: w=0, reads pad
                else                       qv = (yr << 8) | (x0 + 1);
                const bool inband = (qv >> 8) >= r0 && (qv >> 8) < r0 + BANDH;
                qout[j] = inband ? qv : ~qv;
                iout[j] = ((qv >> 8) - r0) * RST + (qv & 255) + 7;
            }
            mwp[it] = make_uint4(pkh(wout[0], wout[0]), pkh(wout[1], wout[1]),
                                 pkh(wout[2], wout[2]), pkh(wout[3], wout[3]));
            mq[it] = make_int2(qout[0], qout[1]);
            mi[it] = make_int2(iout[0], iout[1]);
        }
    }

    // ---- zero pband never-written gaps (NaN guard) + ash k-pad chunks ----
    if (tid < 416) {     // per pair: dwords 0..7 and 68r+72..75 (r=0..10)
        const int pair = tid / 52, j = tid - pair * 52;
        const int off = (j < 8) ? j : RST * ((j - 8) >> 2) + 72 + ((j - 8) & 3);
        pband[pair * XSTP + off] = 0;
    }
    #pragma unroll
    for (int it = 0; it < 2; ++it) {
        const int u = tid + it * BDIM;        // 0..1023
        smem[PB_DW + (u >> 9) * ASH_DW + ((u & 511) >> 3) * AST + 72 + (u & 7)] = 0;
    }

    BWRITE();       // band 0 -> pband
    BLOAD(1);       // issue granule-1 band loads (consumed after next barrier)
    __syncthreads();

    const int wv = tid >> 6, ln = tid & 63, quad = ln >> 4, l16 = ln & 15;
    const int mrow = wv >> 1, ncol = wv & 1;            // 4x2 wave tiling
    const u16* wrow0 = wh + (size_t)(mrow * 32 + l16) * KTOT;
    const int npx0 = ncol * 32 + l16, npx1 = npx0 + 16;

    // ---- sample granule 0 -> ash[0] ----
    {
        const float* xg = x + (((size_t)(b * Cn)) << 12);
        do_sample(pband, smem + PB_DW, xg, mwp[0], mq[0], mi[0], tid);
        if (tid < 64)
            do_sample(pband, smem + PB_DW, xg, mwp[1], mq[1], mi[1], BDIM + tid);
    }
    __syncthreads();

    f32x4 acc[2][2];
    #pragma unroll
    for (int mt = 0; mt < 2; ++mt)
        #pragma unroll
        for (int nt = 0; nt < 2; ++nt) acc[mt][nt] = (f32x4){0.f, 0.f, 0.f, 0.f};

    f16x8 pa[5][2];     // whole-granule A fragments (40 VGPR), loaded 1 ahead
#define APRE(GG) { const int kgp = (GG) * KG + quad * 8; \
        _Pragma("unroll") \
        for (int s = 0; s < 5; ++s) { \
            pa[s][0] = *(const f16x8*)(wrow0 + kgp + s * 32); \
            pa[s][1] = *(const f16x8*)(wrow0 + 16 * KTOT + kgp + s * 32); \
        } }
    APRE(0);

#define MSTEP(S) { \
        const int kd = (S) * 16 + quad * 4; \
        U4H b0, b1; \
        b0.u = *(const uint4*)&ad[npx0 * AST + kd]; \
        b1.u = *(const uint4*)&ad[npx1 * AST + kd]; \
        acc[0][0] = __builtin_amdgcn_mfma_f32_16x16x32_f16(pa[S][0], b0.h, acc[0][0], 0, 0, 0); \
        acc[0][1] = __builtin_amdgcn_mfma_f32_16x16x32_f16(pa[S][0], b1.h, acc[0][1], 0, 0, 0); \
        acc[1][0] = __builtin_amdgcn_mfma_f32_16x16x32_f16(pa[S][1], b0.h, acc[1][0], 0, 0, 0); \
        acc[1][1] = __builtin_amdgcn_mfma_f32_16x16x32_f16(pa[S][1], b1.h, acc[1][1], 0, 0, 0); }

    // ---- pipelined granule loop: 2 barriers/granule, MFMA in BOTH segments ----
    for (int g = 0; g < NG; ++g) {
        const u32* ad = smem + PB_DW + (g & 1) * ASH_DW;        // MFMA(g) source
        u32* ashN     = smem + PB_DW + ((g + 1) & 1) * ASH_DW;  // sample(g+1) dest
        // -- segment B: band-write(g+1) || MFMA(g) steps 0-1 --
        if (g + 1 < NG) BWRITE();
        MSTEP(0);
        MSTEP(1);
        __syncthreads();                                         // pband(g+1) ready
        // -- segment A: band-load(g+2) || sample(g+1) || MFMA(g) steps 2-4 --
        if (g + 2 < NG) BLOAD(g + 2);
        if (g + 1 < NG) {
            const float* xg = x + (((size_t)(b * Cn + (g + 1) * CG)) << 12);
            do_sample(pband, ashN, xg, mwp[0], mq[0], mi[0], tid);
            if (tid < 64)
                do_sample(pband, ashN, xg, mwp[1], mq[1], mi[1], BDIM + tid);
        }
        MSTEP(2);
        MSTEP(3);
        MSTEP(4);
        if (g + 1 < NG) APRE(g + 1);
        __syncthreads();    // ash[(g+1)&1] ready; ash[g&1]/pband reads drained
    }

    // ---- epilogue: transpose via LDS (stride 68, 16B-aligned) -> float4 rows ----
    float* tr = (float*)smem;     // 128 o x 64 px, overlays pband+ash0 (safe)
    #pragma unroll
    for (int mt = 0; mt < 2; ++mt)
        #pragma unroll
        for (int nt = 0; nt < 2; ++nt)
            #pragma unroll
            for (int r = 0; r < 4; ++r) {
                const int o  = mrow * 32 + mt * 16 + quad * 4 + r;
                const int px = ncol * 32 + nt * 16 + l16;
                tr[o * 68 + px] = acc[mt][nt][r] + bias[o];
            }
    __syncthreads();
    {
        const int orow = tid >> 2, f0 = tid & 3;
        #pragma unroll
        for (int it = 0; it < 4; ++it) {
            const int f = f0 + it * 4;
            const float4 v = *(const float4*)&tr[orow * 68 + (f << 2)];
            *(float4*)&out[(((size_t)b * On + orow) * Hn + h) * Wn + (f << 2)] = v;
        }
    }
#undef BLOAD
#undef BWRITE
#undef APRE
#undef MSTEP
}

// ================= fallback: proven R2 fp32 kernel (no d_ws) =================
constexpr int FBD = 256;
constexpr int FB_PXB = 32, FB_CCH = 4, FB_NCT = FB_CCH * KK, FB_MW = KK * FB_PXB;

#define FMA4(A, S, W)                          \
    A.x = fmaf((S).x, (W), A.x);               \
    A.y = fmaf((S).y, (W), A.y);               \
    A.z = fmaf((S).z, (W), A.z);               \
    A.w = fmaf((S).w, (W), A.w);

__global__ __launch_bounds__(FBD, 4)
void dcn_fb_kernel(const float* __restrict__ x,
                   const float* __restrict__ offs,
                   const float* __restrict__ mask,
                   const float* __restrict__ weight,
                   const float* __restrict__ bias,
                   float* __restrict__ out)
{
    __shared__ float wmeta[4 * FB_MW];
    __shared__ int   imeta[4 * FB_MW];
    __shared__ float ssh[FB_NCT * FB_PXB];
    __shared__ float wsh[FB_NCT * On];

    const int tid    = threadIdx.x;
    const int b      = blockIdx.x & 7;
    const int rem    = blockIdx.x >> 3;
    const int h      = rem >> 1;
    const int pxbase = (rem & 1) * FB_PXB;

    for (int e = tid; e < FB_MW; e += FBD) {
        const int t  = e >> 5;
        const int px = e & 31;
        const int pg = pxbase + px;
        const int ty = t / 3, tx = t - ty * 3;
        const float oy = offs[((b * 18 + 2 * t    ) * Hn + h) * Wn + pg];
        const float ox = offs[((b * 18 + 2 * t + 1) * Hn + h) * Wn + pg];
        const float m  = mask[((b * KK + t) * Hn + h) * Wn + pg];
        const float py = (float)(h - PAD + ty) + oy;
        const float qx = (float)(pg - PAD + tx) + ox;
        const float y0 = floorf(py), x0 = floorf(qx);
        const float wy1 = py - y0, wx1 = qx - x0;
        const float wy0 = 1.f - wy1, wx0 = 1.f - wx1;
        const float cw[4] = { wy0 * wx0, wy0 * wx1, wy1 * wx0, wy1 * wx1 };
        #pragma unroll
        for (int k = 0; k < 4; ++k) {
            const float yk = y0 + (float)(k >> 1);
            const float xk = x0 + (float)(k & 1);
            const bool valid = (yk >= 0.f) && (yk <= (float)(Hn - 1)) &&
                               (xk >= 0.f) && (xk <= (float)(Wn - 1));
            const int yc = (int)fminf(fmaxf(yk, 0.f), (float)(Hn - 1));
            const int xc = (int)fminf(fmaxf(xk, 0.f), (float)(Wn - 1));
            wmeta[k * FB_MW + e] = valid ? cw[k] * m : 0.f;
            imeta[k * FB_MW + e] = yc * Wn + xc;
        }
    }
    __syncthreads();

    const int px0 = (tid & 7) << 2;
    const int oo  = (tid >> 3) << 2;

    float4 acc[4];
    #pragma unroll
    for (int j = 0; j < 4; ++j) acc[j] = make_float4(0.f, 0.f, 0.f, 0.f);

    for (int cb = 0; cb < Cn / FB_CCH; ++cb) {
        #pragma unroll
        for (int it = 0; it < (FB_NCT * On) / FBD; ++it) {
            const int e = tid + it * FBD;
            const int r = e >> 7;
            const int o = e & 127;
            wsh[r * On + o] = weight[o * (Cn * KK) + cb * FB_NCT + r];
        }
        for (int e = tid; e < FB_NCT * FB_PXB; e += FBD) {
            const int px = e & 31;
            const int ct = e >> 5;
            const int c  = ct / 9;
            const int mb = (ct - c * 9) * FB_PXB + px;
            const float* xp = x + (((b * Cn) + cb * FB_CCH + c) << 12);
            float v =  wmeta[mb]              * xp[imeta[mb]];
            v = fmaf(wmeta[FB_MW     + mb], xp[imeta[FB_MW     + mb]], v);
            v = fmaf(wmeta[2 * FB_MW + mb], xp[imeta[2 * FB_MW + mb]], v);
            v = fmaf(wmeta[3 * FB_MW + mb], xp[imeta[3 * FB_MW + mb]], v);
            ssh[ct * FB_PXB + px] = v;
        }
        __syncthreads();

        #pragma unroll 6
        for (int ct = 0; ct < FB_NCT; ++ct) {
            const float4 sv = *(const float4*)&ssh[ct * FB_PXB + px0];
            const float4 wa = *(const float4*)&wsh[ct * On + oo];
            FMA4(acc[0], sv, wa.x);
            FMA4(acc[1], sv, wa.y);
            FMA4(acc[2], sv, wa.z);
            FMA4(acc[3], sv, wa.w);
        }
        __syncthreads();
    }

    #pragma unroll
    for (int j = 0; j < 4; ++j) {
        const float bv = bias[oo + j];
        float4 r = acc[j];
        r.x += bv; r.y += bv; r.z += bv; r.w += bv;
        *(float4*)&out[((b * On + oo + j) * Hn + h) * Wn + pxbase + px0] = r;
    }
}

extern "C" void kernel_launch(void* const* d_in, const int* in_sizes, int n_in,
                              void* d_out, int out_size, void* d_ws, size_t ws_size,
                              hipStream_t stream) {
    const float* x      = (const float*)d_in[0];
    const float* offs   = (const float*)d_in[1];
    const float* mask   = (const float*)d_in[2];
    const float* weight = (const float*)d_in[3];
    const float* bias   = (const float*)d_in[4];
    float* out = (float*)d_out;

    const size_t need = (size_t)On * KTOT * sizeof(u16);   // 327,680 B
    if (d_ws != nullptr && ws_size >= need) {
        u16* wh = (u16*)d_ws;
        wprep_kernel<<<dim3(On), dim3(256), 0, stream>>>(weight, wh);
        dcn_mfma_kernel<<<dim3(Bn * Hn), dim3(BDIM), 0, stream>>>(
            x, offs, mask, wh, bias, out);
    } else {
        dcn_fb_kernel<<<dim3(Bn * Hn * 2), dim3(FBD), 0, stream>>>(
            x, offs, mask, weight, bias, out);
    }
}

// Round 4
// 138.902 us; speedup vs baseline: 1.0795x; 1.0795x over previous
//
#include <hip/hip_runtime.h>
#include <math.h>

// DCN v2: B=8, C=128, O=128, H=W=64, k=3, dil=1, dg=1, stride=1, pad=1.
// R12 = R9 register structure + R11 f16 data path.
// R11 post-mortem: whole-granule A prefetch pa[5][2] (40 VGPR live across
// both barriers) blew the 128-VGPR cap -> scratch spills (WRITE_SIZE
// 16384->35840 KB). R12 reverts to R9's proven 2-step prefetch (16 VGPR):
// steps 0-1 prefetched across the barrier, steps 2-4 loaded inline from L2.
// Kept from R11:
//  - f16 data path: v_pk_fma_f16 bilinear interp (4 ops per channel-pair),
//    mfma_f32_16x16x32_f16 GEMM, cvt_pkrtz packing.
//  - AST=84: B-fragments via ds_read_b128, ash writes via 2x ds_write_b128.
//  - RST=68 band row stride (free; conflict theory disproven but harmless).
// LDS 67,200 B -> 2 blocks/CU. __launch_bounds__(512,4) caps VGPR 128.
constexpr int Bn = 8, Cn = 128, On = 128, Hn = 64, Wn = 64;
constexpr int KK = 9, PAD = 1;
constexpr int BDIM = 512;                 // 8 waves
constexpr int PXB  = 64;                  // full row per block
constexpr int CG = 16, NG = Cn / CG;      // 8 channel granules
constexpr int KG = 160, KTOT = NG * KG;   // 1280 (144 real + 16 pad per granule)
constexpr int BANDH = 11;                 // band rows (h-5 .. h+5)
constexpr int RST  = 68;                  // pband row stride (dwords)
constexpr int XSTP = 756;                 // pband pair stride (dwords), 16B-aligned
constexpr int AST  = 84;                  // ash px stride (dwords), 16B-aligned
constexpr int ME   = KK * PXB;            // 576 sampling elements
constexpr int PB_DW  = 8 * XSTP;          // 6048
constexpr int ASH_DW = PXB * AST;         // 5376
constexpr int SM_DW  = PB_DW + 2 * ASH_DW;// 16800 dwords = 67,200 B
constexpr int BUNITS = BANDH * 128;       // 1408 band load/write units

typedef __attribute__((ext_vector_type(2))) _Float16 h2;      // arithmetic
typedef __attribute__((ext_vector_type(8))) __fp16   f16x8;   // MFMA operand
typedef __attribute__((ext_vector_type(4))) float f32x4;
typedef unsigned short u16;
typedef unsigned int u32;

union UH  { u32 u; h2 h; };
union U4H { uint4 u; f16x8 h; };

__device__ __forceinline__ u32 pkh(float a, float b) {  // low16 = f16(a), RTZ
    union { decltype(__builtin_amdgcn_cvt_pkrtz(0.f, 0.f)) p; u32 u; } t;
    t.p = __builtin_amdgcn_cvt_pkrtz(a, b);
    return t.u;
}
__device__ __forceinline__ h2 bch(u32 w) { UH t; t.u = w; return t.h; }
__device__ __forceinline__ u16 f2h(float f) {           // RNE f32->f16
    union { _Float16 h; u16 u; } v; v.h = (_Float16)f; return v.u;
}

// weight [O][C*9] fp32 -> wh [O][KTOT] f16, k' = g*KG + t*16 + cl.
// One block per o: coalesced reads, LDS bounce, coalesced u32 stores.
__global__ void wprep_kernel(const float* __restrict__ w, u16* __restrict__ wh) {
    __shared__ u32 tmpw[KTOT / 2];
    u16* tmp = (u16*)tmpw;
    const int tid = threadIdx.x, o = blockIdx.x;
    if (tid < 64)    // zero pad slices k=144..159 of each granule (dwords 72..79)
        tmpw[(tid >> 3) * 80 + 72 + (tid & 7)] = 0;
    for (int k = tid; k < Cn * KK; k += 256) {
        const int c = k / 9, t = k - 9 * c;
        tmp[(c >> 4) * KG + t * 16 + (c & 15)] = f2h(w[o * (Cn * KK) + k]);
    }
    __syncthreads();
    u32* dst = (u32*)(wh + (size_t)o * KTOT);
    for (int e = tid; e < KTOT / 2; e += 256) dst[e] = tmpw[e];
}

// sampling of one (tap,px) element for one 16-channel granule.
// wp: 4x u32, each = bilinear weight duplicated as packed f16 pair.
__device__ __forceinline__ void do_sample(const u32* __restrict__ pband,
                                          u32* __restrict__ ashW,
                                          const float* __restrict__ xg,
                                          const uint4 wp, const int2 q,
                                          const int2 ix, const int e)
{
    const int t = e >> 6, px = e & 63;
    u32 avp[8];
    if (!__any((q.x | q.y) < 0)) {           // all corners of wave in band
        const u32* p0 = pband + ix.x;
        const u32* p1 = pband + ix.y;
        const h2 w0 = bch(wp.x), w1 = bch(wp.y), w2 = bch(wp.z), w3 = bch(wp.w);
        #pragma unroll
        for (int c2 = 0; c2 < 8; ++c2) {
            const h2 vt0 = bch(p0[c2 * XSTP]), vt1 = bch(p0[c2 * XSTP + 1]);
            const h2 vb0 = bch(p1[c2 * XSTP]), vb1 = bch(p1[c2 * XSTP + 1]);
            const h2 r = w0 * vt0 + w1 * vt1 + w2 * vb0 + w3 * vb1;
            UH o; o.h = r; avp[c2] = o.u;
        }
    } else {                                  // rare: clamped global reads
        const float fw0 = (float)bch(wp.x)[0], fw1 = (float)bch(wp.y)[0];
        const float fw2 = (float)bch(wp.z)[0], fw3 = (float)bch(wp.w)[0];
        const int qx = q.x < 0 ? ~q.x : q.x;
        const int qy = q.y < 0 ? ~q.y : q.y;
        const int yrx = qx >> 8, yry = qy >> 8;
        const int xx = (qx & 255) - 1, xy = (qy & 255) - 1;
        const int ax0 = max(xx, 0), ax1 = min(xx + 1, Wn - 1);
        const int ay0 = max(xy, 0), ay1 = min(xy + 1, Wn - 1);
        #pragma unroll
        for (int c2 = 0; c2 < 8; ++c2) {
            float v2[2];
            #pragma unroll
            for (int sb = 0; sb < 2; ++sb) {
                const float* gc = xg + ((2 * c2 + sb) << 12);
                const float t0 = gc[yrx * Wn + ax0], t1 = gc[yrx * Wn + ax1];
                const float b0 = gc[yry * Wn + ay0], b1 = gc[yry * Wn + ay1];
                v2[sb] = fmaf(fw0, t0, fmaf(fw1, t1, fmaf(fw2, b0, fw3 * b1)));
            }
            avp[c2] = pkh(v2[0], v2[1]);
        }
    }
    u32* d = ashW + px * AST + t * 8;
    *(uint4*)&d[0] = make_uint4(avp[0], avp[1], avp[2], avp[3]);
    *(uint4*)&d[4] = make_uint4(avp[4], avp[5], avp[6], avp[7]);
}

__global__ __launch_bounds__(BDIM, 4)
void dcn_mfma_kernel(const float* __restrict__ x,
                     const float* __restrict__ offs,
                     const float* __restrict__ mask,
                     const u16*   __restrict__ wh,
                     const float* __restrict__ bias,
                     float* __restrict__ out)
{
    __shared__ __align__(16) u32 smem[SM_DW];   // pband | ash0 | ash1
    u32* const pband = smem;

    const int tid = threadIdx.x;
    const int b   = blockIdx.x & 7;             // batch <-> XCD affinity
    const int h   = blockIdx.x >> 3;
    const int r0  = min(max(h - 5, 0), Hn - BANDH);

    const int s_px4 = tid & 15, s_pair = (tid >> 4) & 7;

    float4 bnda[3], bndb[3];
#define BLOAD(GCH) { \
        _Pragma("unroll") \
        for (int it = 0; it < 3; ++it) { \
            const int u = tid + it * BDIM; \
            if (u < BUNITS) { \
                const int row = u >> 7; \
                const float* bp = x + (((size_t)(b * Cn + (GCH) * CG + 2 * s_pair)) << 12) \
                                  + (r0 + row) * Wn + (s_px4 << 2); \
                bnda[it] = *(const float4*)bp; \
                bndb[it] = *(const float4*)(bp + 4096); \
            } \
        } }
#define BWRITE() { \
        _Pragma("unroll") \
        for (int it = 0; it < 3; ++it) { \
            const int u = tid + it * BDIM; \
            if (u < BUNITS) { \
                const int row = u >> 7; \
                u32* d = &pband[s_pair * XSTP + row * RST + 8 + (s_px4 << 2)]; \
                *(uint4*)d = make_uint4( \
                    pkh(bnda[it].x, bndb[it].x), pkh(bnda[it].y, bndb[it].y), \
                    pkh(bnda[it].z, bndb[it].z), pkh(bnda[it].w, bndb[it].w)); \
            } \
        } }

    BLOAD(0);   // issue granule-0 band loads before meta (latency overlap)

    // ---- meta in registers: packed f16 weights mwp, coord code mq, index mi ----
    uint4 mwp[2]; int2 mq[2]; int2 mi[2];
    #pragma unroll
    for (int it = 0; it < 2; ++it) {
        mwp[it] = make_uint4(0, 0, 0, 0);
        mq[it] = make_int2(r0 << 8, r0 << 8);
        mi[it] = make_int2(7, 7);
        const int e = tid + it * BDIM;
        if (e < ME) {
            const int t = e >> 6, px = e & 63;
            const int ty = t / 3, tx = t - ty * 3;
            const float oy = offs[((b * 18 + 2 * t    ) * Hn + h) * Wn + px];
            const float ox = offs[((b * 18 + 2 * t + 1) * Hn + h) * Wn + px];
            const float m  = mask[((b * KK + t) * Hn + h) * Wn + px];
            const float py = (float)(h - PAD + ty) + oy;
            const float qx = (float)(px - PAD + tx) + ox;
            const float fy = floorf(py), fx = floorf(qx);
            const float wy1 = py - fy, wx1 = qx - fx;
            const float wy0 = 1.f - wy1, wx0 = 1.f - wx1;
            const int y0 = (int)fy, x0 = (int)fx;
            const bool cx0 = (x0 >= 0) && (x0 < Wn);
            const bool cx1 = (x0 >= -1) && (x0 < Wn - 1);
            const float wr[2] = { wy0, wy1 };
            float wout[4]; int qout[2], iout[2];
            #pragma unroll
            for (int j = 0; j < 2; ++j) {
                const int yr = y0 + j;
                const bool rv = (yr >= 0) && (yr < Hn);
                wout[2 * j]     = (rv && cx0) ? wr[j] * wx0 * m : 0.f;
                wout[2 * j + 1] = (rv && cx1) ? wr[j] * wx1 * m : 0.f;
                int qv;
                if (!rv || (!cx0 && !cx1)) qv = r0 << 8;   // junk: w=0, reads pad
                else                       qv = (yr << 8) | (x0 + 1);
                const bool inband = (qv >> 8) >= r0 && (qv >> 8) < r0 + BANDH;
                qout[j] = inband ? qv : ~qv;
                iout[j] = ((qv >> 8) - r0) * RST + (qv & 255) + 7;
            }
            mwp[it] = make_uint4(pkh(wout[0], wout[0]), pkh(wout[1], wout[1]),
                                 pkh(wout[2], wout[2]), pkh(wout[3], wout[3]));
            mq[it] = make_int2(qout[0], qout[1]);
            mi[it] = make_int2(iout[0], iout[1]);
        }
    }

    // ---- zero pband never-written gaps (NaN guard) + ash k-pad chunks ----
    if (tid < 416) {     // per pair: dwords 0..7 and 68r+72..75 (r=0..10)
        const int pair = tid / 52, j = tid - pair * 52;
        const int off = (j < 8) ? j : RST * ((j - 8) >> 2) + 72 + ((j - 8) & 3);
        pband[pair * XSTP + off] = 0;
    }
    #pragma unroll
    for (int it = 0; it < 2; ++it) {
        const int u = tid + it * BDIM;        // 0..1023
        smem[PB_DW + (u >> 9) * ASH_DW + ((u & 511) >> 3) * AST + 72 + (u & 7)] = 0;
    }

    BWRITE();       // band 0 -> pband
    BLOAD(1);       // issue granule-1 band loads (consumed after next barrier)
    __syncthreads();

    const int wv = tid >> 6, ln = tid & 63, quad = ln >> 4, l16 = ln & 15;
    const int mrow = wv >> 1, ncol = wv & 1;            // 4x2 wave tiling
    const u16* wrow0 = wh + (size_t)(mrow * 32 + l16) * KTOT;
    const int npx0 = ncol * 32 + l16, npx1 = npx0 + 16;

    // ---- sample granule 0 -> ash[0] ----
    {
        const float* xg = x + (((size_t)(b * Cn)) << 12);
        do_sample(pband, smem + PB_DW, xg, mwp[0], mq[0], mi[0], tid);
        if (tid < 64)
            do_sample(pband, smem + PB_DW, xg, mwp[1], mq[1], mi[1], BDIM + tid);
    }
    __syncthreads();

    f32x4 acc[2][2];
    #pragma unroll
    for (int mt = 0; mt < 2; ++mt)
        #pragma unroll
        for (int nt = 0; nt < 2; ++nt) acc[mt][nt] = (f32x4){0.f, 0.f, 0.f, 0.f};

    f16x8 pa0[2], pa1[2];     // prefetched A fragments for steps 0,1 (16 VGPR)
#define APRE(GG) { const int kgp = (GG) * KG + quad * 8; \
        pa0[0] = *(const f16x8*)(wrow0 + kgp); \
        pa1[0] = *(const f16x8*)(wrow0 + 16 * KTOT + kgp); \
        pa0[1] = *(const f16x8*)(wrow0 + kgp + 32); \
        pa1[1] = *(const f16x8*)(wrow0 + 16 * KTOT + kgp + 32); }
    APRE(0);

#define MSTEP_PRE(S) { \
        const int kd = (S) * 16 + quad * 4; \
        U4H b0, b1; \
        b0.u = *(const uint4*)&ad[npx0 * AST + kd]; \
        b1.u = *(const uint4*)&ad[npx1 * AST + kd]; \
        acc[0][0] = __builtin_amdgcn_mfma_f32_16x16x32_f16(pa0[S], b0.h, acc[0][0], 0, 0, 0); \
        acc[0][1] = __builtin_amdgcn_mfma_f32_16x16x32_f16(pa0[S], b1.h, acc[0][1], 0, 0, 0); \
        acc[1][0] = __builtin_amdgcn_mfma_f32_16x16x32_f16(pa1[S], b0.h, acc[1][0], 0, 0, 0); \
        acc[1][1] = __builtin_amdgcn_mfma_f32_16x16x32_f16(pa1[S], b1.h, acc[1][1], 0, 0, 0); }

#define MSTEP_LD(S) { \
        const int kg = g * KG + (S) * 32 + quad * 8; \
        const f16x8 a0 = *(const f16x8*)(wrow0 + kg); \
        const f16x8 a1 = *(const f16x8*)(wrow0 + 16 * KTOT + kg); \
        const int kd = (S) * 16 + quad * 4; \
        U4H b0, b1; \
        b0.u = *(const uint4*)&ad[npx0 * AST + kd]; \
        b1.u = *(const uint4*)&ad[npx1 * AST + kd]; \
        acc[0][0] = __builtin_amdgcn_mfma_f32_16x16x32_f16(a0, b0.h, acc[0][0], 0, 0, 0); \
        acc[0][1] = __builtin_amdgcn_mfma_f32_16x16x32_f16(a0, b1.h, acc[0][1], 0, 0, 0); \
        acc[1][0] = __builtin_amdgcn_mfma_f32_16x16x32_f16(a1, b0.h, acc[1][0], 0, 0, 0); \
        acc[1][1] = __builtin_amdgcn_mfma_f32_16x16x32_f16(a1, b1.h, acc[1][1], 0, 0, 0); }

    // ---- pipelined granule loop: 2 barriers/granule, MFMA in BOTH segments ----
    for (int g = 0; g < NG; ++g) {
        const u32* ad = smem + PB_DW + (g & 1) * ASH_DW;        // MFMA(g) source
        u32* ashN     = smem + PB_DW + ((g + 1) & 1) * ASH_DW;  // sample(g+1) dest
        // -- segment B: band-write(g+1) || MFMA(g) steps 0-1 --
        if (g + 1 < NG) BWRITE();
        MSTEP_PRE(0);
        MSTEP_PRE(1);
        __syncthreads();                                         // pband(g+1) ready
        // -- segment A: band-load(g+2) || sample(g+1) || MFMA(g) steps 2-4 --
        if (g + 2 < NG) BLOAD(g + 2);
        if (g + 1 < NG) {
            const float* xg = x + (((size_t)(b * Cn + (g + 1) * CG)) << 12);
            do_sample(pband, ashN, xg, mwp[0], mq[0], mi[0], tid);
            if (tid < 64)
                do_sample(pband, ashN, xg, mwp[1], mq[1], mi[1], BDIM + tid);
        }
        MSTEP_LD(2);
        MSTEP_LD(3);
        MSTEP_LD(4);
        if (g + 1 < NG) APRE(g + 1);
        __syncthreads();    // ash[(g+1)&1] ready; ash[g&1]/pband reads drained
    }

    // ---- epilogue: transpose via LDS (stride 68, 16B-aligned) -> float4 rows ----
    float* tr = (float*)smem;     // 128 o x 64 px, overlays pband+ash0 (safe)
    #pragma unroll
    for (int mt = 0; mt < 2; ++mt)
        #pragma unroll
        for (int nt = 0; nt < 2; ++nt)
            #pragma unroll
            for (int r = 0; r < 4; ++r) {
                const int o  = mrow * 32 + mt * 16 + quad * 4 + r;
                const int px = ncol * 32 + nt * 16 + l16;
                tr[o * 68 + px] = acc[mt][nt][r] + bias[o];
            }
    __syncthreads();
    {
        const int orow = tid >> 2, f0 = tid & 3;
        #pragma unroll
        for (int it = 0; it < 4; ++it) {
            const int f = f0 + it * 4;
            const float4 v = *(const float4*)&tr[orow * 68 + (f << 2)];
            *(float4*)&out[(((size_t)b * On + orow) * Hn + h) * Wn + (f << 2)] = v;
        }
    }
#undef BLOAD
#undef BWRITE
#undef APRE
#undef MSTEP_PRE
#undef MSTEP_LD
}

// ================= fallback: proven R2 fp32 kernel (no d_ws) =================
constexpr int FBD = 256;
constexpr int FB_PXB = 32, FB_CCH = 4, FB_NCT = FB_CCH * KK, FB_MW = KK * FB_PXB;

#define FMA4(A, S, W)                          \
    A.x = fmaf((S).x, (W), A.x);               \
    A.y = fmaf((S).y, (W), A.y);               \
    A.z = fmaf((S).z, (W), A.z);               \
    A.w = fmaf((S).w, (W), A.w);

__global__ __launch_bounds__(FBD, 4)
void dcn_fb_kernel(const float* __restrict__ x,
                   const float* __restrict__ offs,
                   const float* __restrict__ mask,
                   const float* __restrict__ weight,
                   const float* __restrict__ bias,
                   float* __restrict__ out)
{
    __shared__ float wmeta[4 * FB_MW];
    __shared__ int   imeta[4 * FB_MW];
    __shared__ float ssh[FB_NCT * FB_PXB];
    __shared__ float wsh[FB_NCT * On];

    const int tid    = threadIdx.x;
    const int b      = blockIdx.x & 7;
    const int rem    = blockIdx.x >> 3;
    const int h      = rem >> 1;
    const int pxbase = (rem & 1) * FB_PXB;

    for (int e = tid; e < FB_MW; e += FBD) {
        const int t  = e >> 5;
        const int px = e & 31;
        const int pg = pxbase + px;
        const int ty = t / 3, tx = t - ty * 3;
        const float oy = offs[((b * 18 + 2 * t    ) * Hn + h) * Wn + pg];
        const float ox = offs[((b * 18 + 2 * t + 1) * Hn + h) * Wn + pg];
        const float m  = mask[((b * KK + t) * Hn + h) * Wn + pg];
        const float py = (float)(h - PAD + ty) + oy;
        const float qx = (float)(pg - PAD + tx) + ox;
        const float y0 = floorf(py), x0 = floorf(qx);
        const float wy1 = py - y0, wx1 = qx - x0;
        const float wy0 = 1.f - wy1, wx0 = 1.f - wx1;
        const float cw[4] = { wy0 * wx0, wy0 * wx1, wy1 * wx0, wy1 * wx1 };
        #pragma unroll
        for (int k = 0; k < 4; ++k) {
            const float yk = y0 + (float)(k >> 1);
            const float xk = x0 + (float)(k & 1);
            const bool valid = (yk >= 0.f) && (yk <= (float)(Hn - 1)) &&
                               (xk >= 0.f) && (xk <= (float)(Wn - 1));
            const int yc = (int)fminf(fmaxf(yk, 0.f), (float)(Hn - 1));
            const int xc = (int)fminf(fmaxf(xk, 0.f), (float)(Wn - 1));
            wmeta[k * FB_MW + e] = valid ? cw[k] * m : 0.f;
            imeta[k * FB_MW + e] = yc * Wn + xc;
        }
    }
    __syncthreads();

    const int px0 = (tid & 7) << 2;
    const int oo  = (tid >> 3) << 2;

    float4 acc[4];
    #pragma unroll
    for (int j = 0; j < 4; ++j) acc[j] = make_float4(0.f, 0.f, 0.f, 0.f);

    for (int cb = 0; cb < Cn / FB_CCH; ++cb) {
        #pragma unroll
        for (int it = 0; it < (FB_NCT * On) / FBD; ++it) {
            const int e = tid + it * FBD;
            const int r = e >> 7;
            const int o = e & 127;
            wsh[r * On + o] = weight[o * (Cn * KK) + cb * FB_NCT + r];
        }
        for (int e = tid; e < FB_NCT * FB_PXB; e += FBD) {
            const int px = e & 31;
            const int ct = e >> 5;
            const int c  = ct / 9;
            const int mb = (ct - c * 9) * FB_PXB + px;
            const float* xp = x + (((b * Cn) + cb * FB_CCH + c) << 12);
            float v =  wmeta[mb]              * xp[imeta[mb]];
            v = fmaf(wmeta[FB_MW     + mb], xp[imeta[FB_MW     + mb]], v);
            v = fmaf(wmeta[2 * FB_MW + mb], xp[imeta[2 * FB_MW + mb]], v);
            v = fmaf(wmeta[3 * FB_MW + mb], xp[imeta[3 * FB_MW + mb]], v);
            ssh[ct * FB_PXB + px] = v;
        }
        __syncthreads();

        #pragma unroll 6
        for (int ct = 0; ct < FB_NCT; ++ct) {
            const float4 sv = *(const float4*)&ssh[ct * FB_PXB + px0];
            const float4 wa = *(const float4*)&wsh[ct * On + oo];
            FMA4(acc[0], sv, wa.x);
            FMA4(acc[1], sv, wa.y);
            FMA4(acc[2], sv, wa.z);
            FMA4(acc[3], sv, wa.w);
        }
        __syncthreads();
    }

    #pragma unroll
    for (int j = 0; j < 4; ++j) {
        const float bv = bias[oo + j];
        float4 r = acc[j];
        r.x += bv; r.y += bv; r.z += bv; r.w += bv;
        *(float4*)&out[((b * On + oo + j) * Hn + h) * Wn + pxbase + px0] = r;
    }
}

extern "C" void kernel_launch(void* const* d_in, const int* in_sizes, int n_in,
                              void* d_out, int out_size, void* d_ws, size_t ws_size,
                              hipStream_t stream) {
    const float* x      = (const float*)d_in[0];
    const float* offs   = (const float*)d_in[1];
    const float* mask   = (const float*)d_in[2];
    const float* weight = (const float*)d_in[3];
    const float* bias   = (const float*)d_in[4];
    float* out = (float*)d_out;

    const size_t need = (size_t)On * KTOT * sizeof(u16);   // 327,680 B
    if (d_ws != nullptr && ws_size >= need) {
        u16* wh = (u16*)d_ws;
        wprep_kernel<<<dim3(On), dim3(256), 0, stream>>>(weight, wh);
        dcn_mfma_kernel<<<dim3(Bn * Hn), dim3(BDIM), 0, stream>>>(
            x, offs, mask, wh, bias, out);
    } else {
        dcn_fb_kernel<<<dim3(Bn * Hn * 2), dim3(FBD), 0, stream>>>(
            x, offs, mask, weight, bias, out);
    }
}